// Round 1
// baseline (466.107 us; speedup 1.0000x reference)
//
#include <hip/hip_runtime.h>

#define HW 160000   // 400*400
#define WIMG 400

// -------------------------------------------------------------------------
// conv1: x[B,3,400,400] -> leaky(conv 3->6, k3 s2 p1) restricted to out
// region [0..63]x[0..63]  (receptive field of the palette 4x4).
// out layout: [B,6,64,64] flat. Grid covers exactly B*6*64*64 = 393216.
// -------------------------------------------------------------------------
__global__ __launch_bounds__(256) void conv1_k(const float* __restrict__ x,
                                               const float* __restrict__ w,
                                               const float* __restrict__ bias,
                                               float* __restrict__ out) {
  int idx = blockIdx.x * 256 + threadIdx.x;
  int j = idx & 63;
  int i = (idx >> 6) & 63;
  int o = (idx >> 12) % 6;
  int b = idx / (6 * 4096);
  float acc = bias[o];
#pragma unroll
  for (int c = 0; c < 3; c++) {
    const float* xc = x + (size_t)(b * 3 + c) * HW;
    const float* wc = w + (o * 3 + c) * 9;
#pragma unroll
    for (int di = 0; di < 3; di++) {
      int xi = 2 * i - 1 + di;
      if (xi < 0) continue;
#pragma unroll
      for (int dj = 0; dj < 3; dj++) {
        int xj = 2 * j - 1 + dj;
        if (xj < 0) continue;
        acc = fmaf(xc[xi * WIMG + xj], wc[di * 3 + dj], acc);
      }
    }
  }
  out[idx] = acc >= 0.f ? acc : 0.01f * acc;
}

// -------------------------------------------------------------------------
// tail: conv2..conv6 for one batch per block, all intermediates in LDS.
//   conv2: in c1[b,6,64,64] -> 12x32x32 (accumulated in regs, staged tile)
//   conv3: 12x16x16   conv4: 12x8x8   conv5: 6x4x4   conv6(1x1)+relu: 3x4x4
// pal layout: [B,3,16], k = row*4+col.
// LDS: xs (16KB: conv1-channel tile, then conv3 out) + s2 (48KB: conv2 out,
// then conv4 out at [0..768) and conv5 out at [1024..1120)).
// -------------------------------------------------------------------------
__global__ __launch_bounds__(256) void tail_k(
    const float* __restrict__ c1, const float* __restrict__ w2,
    const float* __restrict__ b2, const float* __restrict__ w3,
    const float* __restrict__ b3, const float* __restrict__ w4,
    const float* __restrict__ b4, const float* __restrict__ w5,
    const float* __restrict__ b5, const float* __restrict__ w6,
    const float* __restrict__ b6, float* __restrict__ pal) {
  __shared__ float xs[4096];   // 16 KB
  __shared__ float s2[12288];  // 48 KB
  int tid = threadIdx.x;
  int b = blockIdx.x;

  // ---- conv2: 12x32x32 outputs, 48 per thread, accumulate in registers ----
  float acc[48];
#pragma unroll
  for (int r = 0; r < 48; r++) {
    int o = (tid + 256 * r) >> 10;
    acc[r] = b2[o];
  }
  for (int c = 0; c < 6; c++) {
    __syncthreads();
    for (int t = tid; t < 4096; t += 256)
      xs[t] = c1[(size_t)(b * 6 + c) * 4096 + t];
    __syncthreads();
#pragma unroll
    for (int r = 0; r < 48; r++) {
      int idx = tid + 256 * r;
      int j = idx & 31, i = (idx >> 5) & 31, o = idx >> 10;
      const float* wc = w2 + (o * 6 + c) * 9;
#pragma unroll
      for (int di = 0; di < 3; di++) {
        int xi = 2 * i - 1 + di;
        if (xi < 0) continue;
#pragma unroll
        for (int dj = 0; dj < 3; dj++) {
          int xj = 2 * j - 1 + dj;
          if (xj < 0) continue;
          acc[r] = fmaf(xs[xi * 64 + xj], wc[di * 3 + dj], acc[r]);
        }
      }
    }
  }
  __syncthreads();
#pragma unroll
  for (int r = 0; r < 48; r++) {
    int idx = tid + 256 * r;
    float v = acc[r];
    s2[idx] = v >= 0.f ? v : 0.01f * v;
  }
  __syncthreads();

  // ---- conv3: 12x16x16 -> xs ----
#pragma unroll
  for (int r = 0; r < 12; r++) {
    int idx = tid + 256 * r;
    int j = idx & 15, i = (idx >> 4) & 15, o = idx >> 8;
    float a = b3[o];
    for (int c = 0; c < 12; c++) {
      const float* wc = w3 + (o * 12 + c) * 9;
      const float* sc = s2 + c * 1024;
#pragma unroll
      for (int di = 0; di < 3; di++) {
        int xi = 2 * i - 1 + di;
        if (xi < 0) continue;
#pragma unroll
        for (int dj = 0; dj < 3; dj++) {
          int xj = 2 * j - 1 + dj;
          if (xj < 0) continue;
          a = fmaf(sc[xi * 32 + xj], wc[di * 3 + dj], a);
        }
      }
    }
    xs[idx] = a >= 0.f ? a : 0.01f * a;
  }
  __syncthreads();

  // ---- conv4: 12x8x8 -> s2[0..768) ----
#pragma unroll
  for (int r = 0; r < 3; r++) {
    int idx = tid + 256 * r;
    int j = idx & 7, i = (idx >> 3) & 7, o = idx >> 6;
    float a = b4[o];
    for (int c = 0; c < 12; c++) {
      const float* wc = w4 + (o * 12 + c) * 9;
      const float* sc = xs + c * 256;
#pragma unroll
      for (int di = 0; di < 3; di++) {
        int xi = 2 * i - 1 + di;
        if (xi < 0) continue;
#pragma unroll
        for (int dj = 0; dj < 3; dj++) {
          int xj = 2 * j - 1 + dj;
          if (xj < 0) continue;
          a = fmaf(sc[xi * 16 + xj], wc[di * 3 + dj], a);
        }
      }
    }
    s2[idx] = a >= 0.f ? a : 0.01f * a;
  }
  __syncthreads();

  // ---- conv5: 6x4x4 -> s2[1024..1120) ----
  if (tid < 96) {
    int j = tid & 3, i = (tid >> 2) & 3, o = tid >> 4;
    float a = b5[o];
    for (int c = 0; c < 12; c++) {
      const float* wc = w5 + (o * 12 + c) * 9;
      const float* sc = s2 + c * 64;
#pragma unroll
      for (int di = 0; di < 3; di++) {
        int xi = 2 * i - 1 + di;
        if (xi < 0) continue;
#pragma unroll
        for (int dj = 0; dj < 3; dj++) {
          int xj = 2 * j - 1 + dj;
          if (xj < 0) continue;
          a = fmaf(sc[xi * 8 + xj], wc[di * 3 + dj], a);
        }
      }
    }
    s2[1024 + tid] = a >= 0.f ? a : 0.01f * a;  // layout o*16 + i*4 + j == tid
  }
  __syncthreads();

  // ---- conv6 (1x1) + relu -> pal[b,3,16] ----
  if (tid < 48) {
    int k = tid & 15, o = tid >> 4;
    float a = b6[o];
#pragma unroll
    for (int c = 0; c < 6; c++) a = fmaf(s2[1024 + c * 16 + k], w6[o * 6 + c], a);
    pal[b * 48 + o * 16 + k] = a > 0.f ? a : 0.f;
  }
}

// -------------------------------------------------------------------------
// gather: per pixel, max over 16 logits; sum pal colors over all bitwise-
// tied maxima (reproduces softmax-equality tie semantics exactly, since
// softmax is monotone and ties in probs <=> bitwise-equal fp32 logits).
// 4 pixels/thread via float4; 16 coalesced channel streams.
// -------------------------------------------------------------------------
__global__ __launch_bounds__(256) void gather_k(const float* __restrict__ logits,
                                                const float* __restrict__ pal,
                                                float* __restrict__ out) {
  __shared__ float ps[48];
  int b = blockIdx.y;
  int tid = threadIdx.x;
  if (tid < 48) ps[tid] = pal[b * 48 + tid];
  __syncthreads();
  int q = blockIdx.x * 256 + tid;
  if (q >= HW / 4) return;
  int p = q * 4;
  const float* lg = logits + (size_t)b * 16 * HW + p;

  float a[4][16];
#pragma unroll
  for (int k = 0; k < 16; k++) {
    float4 t = *(const float4*)(lg + (size_t)k * HW);
    a[0][k] = t.x; a[1][k] = t.y; a[2][k] = t.z; a[3][k] = t.w;
  }
  float res[4][3];
#pragma unroll
  for (int pp = 0; pp < 4; pp++) {
    float mx = a[pp][0];
#pragma unroll
    for (int k = 1; k < 16; k++) mx = fmaxf(mx, a[pp][k]);
    float r0 = 0.f, r1 = 0.f, r2 = 0.f;
#pragma unroll
    for (int k = 0; k < 16; k++) {
      bool m = (a[pp][k] == mx);
      r0 += m ? ps[k] : 0.f;
      r1 += m ? ps[16 + k] : 0.f;
      r2 += m ? ps[32 + k] : 0.f;
    }
    res[pp][0] = r0; res[pp][1] = r1; res[pp][2] = r2;
  }
  float* ob = out + (size_t)b * 3 * HW + p;
  *(float4*)(ob) = make_float4(res[0][0], res[1][0], res[2][0], res[3][0]);
  *(float4*)(ob + HW) = make_float4(res[0][1], res[1][1], res[2][1], res[3][1]);
  *(float4*)(ob + 2 * HW) = make_float4(res[0][2], res[1][2], res[2][2], res[3][2]);
}

extern "C" void kernel_launch(void* const* d_in, const int* in_sizes, int n_in,
                              void* d_out, int out_size, void* d_ws, size_t ws_size,
                              hipStream_t stream) {
  const float* x     = (const float*)d_in[0];
  const float* blog  = (const float*)d_in[1];
  const float* w1    = (const float*)d_in[2];
  const float* b1    = (const float*)d_in[3];
  const float* w2    = (const float*)d_in[4];
  const float* b2    = (const float*)d_in[5];
  const float* w3    = (const float*)d_in[6];
  const float* b3    = (const float*)d_in[7];
  const float* w4    = (const float*)d_in[8];
  const float* b4    = (const float*)d_in[9];
  const float* w5    = (const float*)d_in[10];
  const float* b5    = (const float*)d_in[11];
  const float* w6    = (const float*)d_in[12];
  const float* b6    = (const float*)d_in[13];
  float* out = (float*)d_out;

  float* ws0 = (float*)d_ws;            // conv1 out: 16*6*64*64 = 393216 floats
  float* ws1 = ws0 + 16 * 6 * 64 * 64;  // pal: 16*3*16 = 768 floats

  conv1_k<<<1536, 256, 0, stream>>>(x, w1, b1, ws0);
  tail_k<<<16, 256, 0, stream>>>(ws0, w2, b2, w3, b3, w4, b4, w5, b5, w6, b6, ws1);
  gather_k<<<dim3((HW / 4 + 255) / 256, 16), 256, 0, stream>>>(blog, ws1, out);
}

// Round 2
// 336.621 us; speedup vs baseline: 1.3847x; 1.3847x over previous
//
#include <hip/hip_runtime.h>

#define HW 160000   // 400*400
#define WIMG 400

// -------------------------------------------------------------------------
// conv1: x[B,3,400,400] -> leaky(conv 3->6, k3 s2 p1) restricted to out
// region [0..63]^2 (receptive field of the palette 4x4).
// out: c1[B,6,64,64]. Grid covers exactly 16*6*64*64 = 393216 threads.
// -------------------------------------------------------------------------
__global__ __launch_bounds__(256) void conv1_k(const float* __restrict__ x,
                                               const float* __restrict__ w,
                                               const float* __restrict__ bias,
                                               float* __restrict__ out) {
  int idx = blockIdx.x * 256 + threadIdx.x;
  int j = idx & 63;
  int i = (idx >> 6) & 63;
  int t = idx >> 12;
  int o = t % 6;
  int b = t / 6;
  float acc = bias[o];
#pragma unroll
  for (int c = 0; c < 3; c++) {
    const float* xc = x + (size_t)(b * 3 + c) * HW;
    const float* wc = w + (o * 3 + c) * 9;
#pragma unroll
    for (int di = 0; di < 3; di++) {
      int xi = 2 * i - 1 + di;
      if (xi < 0) continue;
#pragma unroll
      for (int dj = 0; dj < 3; dj++) {
        int xj = 2 * j - 1 + dj;
        if (xj < 0) continue;
        acc = fmaf(xc[xi * WIMG + xj], wc[di * 3 + dj], acc);
      }
    }
  }
  out[idx] = acc >= 0.f ? acc : 0.01f * acc;
}

// Generic strided 3x3 s2 p1 conv + leaky, flat-parallel, input NCHW in ws.
// N = output spatial dim (input is 2N x 2N). CIN channels. One thread/output.
template <int N, int CIN>
__global__ __launch_bounds__(256) void convs_k(const float* __restrict__ in,
                                               const float* __restrict__ w,
                                               const float* __restrict__ bias,
                                               float* __restrict__ out,
                                               int cout) {
  int idx = blockIdx.x * 256 + threadIdx.x;
  int j = idx & (N - 1);
  int i = (idx / N) & (N - 1);
  int t = idx / (N * N);
  int o = t % cout;
  int b = t / cout;
  float acc = bias[o];
#pragma unroll
  for (int c = 0; c < CIN; c++) {
    const float* xc = in + (size_t)(b * CIN + c) * (4 * N * N);
    const float* wc = w + (o * CIN + c) * 9;
#pragma unroll
    for (int di = 0; di < 3; di++) {
      int xi = 2 * i - 1 + di;
      if (xi < 0) continue;
#pragma unroll
      for (int dj = 0; dj < 3; dj++) {
        int xj = 2 * j - 1 + dj;
        if (xj < 0) continue;
        acc = fmaf(xc[xi * 2 * N + xj], wc[di * 3 + dj], acc);
      }
    }
  }
  out[idx] = acc >= 0.f ? acc : 0.01f * acc;
}

// conv6: 1x1, 6->3, relu. in c5[B,6,4,4]; out pal[B,3,16], k=i*4+j.
// 768 threads total.
__global__ __launch_bounds__(256) void conv6_k(const float* __restrict__ c5,
                                               const float* __restrict__ w,
                                               const float* __restrict__ bias,
                                               float* __restrict__ pal) {
  int idx = blockIdx.x * 256 + threadIdx.x;
  int k = idx & 15;
  int t = idx >> 4;
  int o = t % 3;
  int b = t / 3;
  float a = bias[o];
#pragma unroll
  for (int c = 0; c < 6; c++) a = fmaf(c5[b * 96 + c * 16 + k], w[o * 6 + c], a);
  pal[b * 48 + o * 16 + k] = a > 0.f ? a : 0.f;
}

// -------------------------------------------------------------------------
// gather: per pixel, running max over the 16 fp32 logits with tie-sum:
// greater -> reset RGB to pal[k]; equal -> add pal[k]. Reproduces the
// reference's (probs == max) one-hot-with-ties contraction exactly
// (softmax is monotone; ties <=> bitwise-equal logits).
// Streaming: 4 pixels/thread (float4/channel), ~12 live state VGPRs.
// -------------------------------------------------------------------------
__global__ __launch_bounds__(256) void gather_k(const float* __restrict__ logits,
                                                const float* __restrict__ pal,
                                                float* __restrict__ out) {
  __shared__ float ps[48];
  int b = blockIdx.y;
  int tid = threadIdx.x;
  if (tid < 48) ps[tid] = pal[b * 48 + tid];
  __syncthreads();
  int q = blockIdx.x * 256 + tid;
  if (q >= HW / 4) return;
  const float* lg = logits + (size_t)b * 16 * HW + q * 4;

  float4 v = *(const float4*)(lg);
  float mx[4] = {v.x, v.y, v.z, v.w};
  float p0 = ps[0], p1 = ps[16], p2 = ps[32];
  float r0[4] = {p0, p0, p0, p0};
  float r1[4] = {p1, p1, p1, p1};
  float r2[4] = {p2, p2, p2, p2};

#pragma unroll
  for (int k = 1; k < 16; k++) {
    float4 t = *(const float4*)(lg + (size_t)k * HW);
    float q0 = ps[k], q1 = ps[16 + k], q2 = ps[32 + k];
    float vv[4] = {t.x, t.y, t.z, t.w};
#pragma unroll
    for (int pp = 0; pp < 4; pp++) {
      float val = vv[pp];
      bool gt = val > mx[pp];
      bool ge = val >= mx[pp];
      mx[pp] = ge ? val : mx[pp];
      r0[pp] = (gt ? 0.f : r0[pp]) + (ge ? q0 : 0.f);
      r1[pp] = (gt ? 0.f : r1[pp]) + (ge ? q1 : 0.f);
      r2[pp] = (gt ? 0.f : r2[pp]) + (ge ? q2 : 0.f);
    }
  }
  float* ob = out + (size_t)b * 3 * HW + q * 4;
  *(float4*)(ob) = make_float4(r0[0], r0[1], r0[2], r0[3]);
  *(float4*)(ob + HW) = make_float4(r1[0], r1[1], r1[2], r1[3]);
  *(float4*)(ob + 2 * HW) = make_float4(r2[0], r2[1], r2[2], r2[3]);
}

extern "C" void kernel_launch(void* const* d_in, const int* in_sizes, int n_in,
                              void* d_out, int out_size, void* d_ws, size_t ws_size,
                              hipStream_t stream) {
  const float* x    = (const float*)d_in[0];
  const float* blog = (const float*)d_in[1];
  const float* w1 = (const float*)d_in[2];
  const float* b1 = (const float*)d_in[3];
  const float* w2 = (const float*)d_in[4];
  const float* b2 = (const float*)d_in[5];
  const float* w3 = (const float*)d_in[6];
  const float* b3 = (const float*)d_in[7];
  const float* w4 = (const float*)d_in[8];
  const float* b4 = (const float*)d_in[9];
  const float* w5 = (const float*)d_in[10];
  const float* b5 = (const float*)d_in[11];
  const float* w6 = (const float*)d_in[12];
  const float* b6 = (const float*)d_in[13];
  float* out = (float*)d_out;

  float* c1  = (float*)d_ws;            // [16,6,64,64]  393216
  float* c2  = c1 + 16 * 6 * 64 * 64;   // [16,12,32,32] 196608
  float* c3  = c2 + 16 * 12 * 32 * 32;  // [16,12,16,16] 49152
  float* c4  = c3 + 16 * 12 * 16 * 16;  // [16,12,8,8]   12288
  float* c5  = c4 + 16 * 12 * 8 * 8;    // [16,6,4,4]    1536
  float* pal = c5 + 16 * 6 * 4 * 4;     // [16,3,16]     768

  conv1_k<<<1536, 256, 0, stream>>>(x, w1, b1, c1);
  convs_k<32, 6><<<768, 256, 0, stream>>>(c1, w2, b2, c2, 12);
  convs_k<16, 12><<<192, 256, 0, stream>>>(c2, w3, b3, c3, 12);
  convs_k<8, 12><<<48, 256, 0, stream>>>(c3, w4, b4, c4, 12);
  convs_k<4, 12><<<6, 256, 0, stream>>>(c4, w5, b5, c5, 6);
  conv6_k<<<3, 256, 0, stream>>>(c5, w6, b6, pal);
  gather_k<<<dim3((HW / 4 + 255) / 256, 16), 256, 0, stream>>>(blog, pal, out);
}